// Round 1
// 229.058 us; speedup vs baseline: 1.0787x; 1.0787x over previous
//
#include <hip/hip_runtime.h>

#define T_ROWS 32
#define NROWS  65536
#define CDIM   128
#define MKEYS  1024

typedef _Float16 half8 __attribute__((ext_vector_type(8)));
typedef _Float16 half4 __attribute__((ext_vector_type(4)));
typedef float    floatx4 __attribute__((ext_vector_type(4)));

union FU { float f; unsigned u; };

#define MFMA16 __builtin_amdgcn_mfma_f32_16x16x32_f16

// ---------------- Kernel A: convert keys fp32 -> fp16 (row-major [1024][128]) --------
__global__ __launch_bounds__(256) void cvt_keys_kernel(const float* __restrict__ keys,
                                                       _Float16* __restrict__ kh) {
    int i = blockIdx.x * 256 + threadIdx.x;          // 32768 threads, 4 elems each
    float4 f = ((const float4*)keys)[i];
    half4 hv;
    hv[0] = (_Float16)f.x; hv[1] = (_Float16)f.y;
    hv[2] = (_Float16)f.z; hv[3] = (_Float16)f.w;
    ((half4*)kh)[i] = hv;
}

// ---------------- Kernel B: fused score/argmax/rescue/gather, 32 rows/block ----------
// Two-MFMA-pass design: pass A computes running per-row max (fp16-MFMA approx),
// pass B recomputes the IDENTICAL MFMA chain (deterministic -> bit-equal scores)
// and collects candidates >= M1 - 2*e1 - slack. True fp32 argmax is provably in
// the candidate set (|s~ - s| <= e1 for every key). Exact fp32 rescore decides.
__global__ __launch_bounds__(256, 4) void gather_main(
    const float* __restrict__ q,      // trend_representation (65536x128)
    const float* __restrict__ rep,    // representation
    const float* __restrict__ keys,   // fp32 keys (1024x128)
    const float* __restrict__ vals,   // fp32 values
    const _Float16* __restrict__ kh,  // fp16 keys (ws)
    float* __restrict__ out)          // [131072]: keys_g then values_g
{
    __shared__ _Float16 qh[T_ROWS][128];          // fp16 q, swizzled (8 KB)
    __shared__ float qss[T_ROWS][17];             // per-(row,c8) sumsq, padded
    __shared__ float wm1[4][T_ROWS];
    __shared__ int   wi1[4][T_ROWS];
    __shared__ float rowT[T_ROWS];
    __shared__ int   rowI1s[T_ROWS];
    __shared__ int   candCnt[T_ROWS];
    __shared__ int   candKey[T_ROWS][8];
    __shared__ int   rowOvf[T_ROWS];
    __shared__ unsigned long long rowBest[T_ROWS];
    __shared__ int   rowIdx[T_ROWS];
    __shared__ float kgp[T_ROWS][17], vgp[T_ROWS][17];

    const int t    = threadIdx.x;
    const int wid  = t >> 6;
    const int lane = t & 63;
    const int n    = lane & 15;       // A: key-in-16, B/C: q-row (col) in 16
    const int quad = lane >> 4;       // k-chunk selector / C row group
    const long g0  = (long)blockIdx.x * T_ROWS;

    if (t < T_ROWS) { candCnt[t] = 0; rowOvf[t] = 0; rowBest[t] = 0ull; }

    // ---- P1: stage q tile -> fp16 LDS (swizzled), per-(row,chunk) sumsq ----
    {
        int row = t >> 4, c8 = t & 15;
        #pragma unroll
        for (int h = 0; h < 2; ++h) {
            int rr = row + h * 16;
            const float4* src = (const float4*)(q + (g0 + rr) * CDIM + c8 * 8);
            float4 a0 = src[0], a1 = src[1];
            qss[rr][c8] = a0.x*a0.x + a0.y*a0.y + a0.z*a0.z + a0.w*a0.w
                        + a1.x*a1.x + a1.y*a1.y + a1.z*a1.z + a1.w*a1.w;
            half8 hv;
            hv[0] = (_Float16)a0.x; hv[1] = (_Float16)a0.y;
            hv[2] = (_Float16)a0.z; hv[3] = (_Float16)a0.w;
            hv[4] = (_Float16)a1.x; hv[5] = (_Float16)a1.y;
            hv[6] = (_Float16)a1.z; hv[7] = (_Float16)a1.w;
            int phys = c8 ^ (rr & 7);
            *(half8*)&qh[rr][phys * 8] = hv;
        }
    }
    __syncthreads();

    // ---- P2: hoist B-fragments (q rows n and 16+n) into registers ----
    half8 qa0, qa1, qa2, qa3, qb0, qb1, qb2, qb3;
    {
        int x = n & 7;
        qa0 = *(const half8*)&qh[n][((0 * 4 + quad) ^ x) * 8];
        qa1 = *(const half8*)&qh[n][((1 * 4 + quad) ^ x) * 8];
        qa2 = *(const half8*)&qh[n][((2 * 4 + quad) ^ x) * 8];
        qa3 = *(const half8*)&qh[n][((3 * 4 + quad) ^ x) * 8];
        qb0 = *(const half8*)&qh[16 + n][((0 * 4 + quad) ^ x) * 8];
        qb1 = *(const half8*)&qh[16 + n][((1 * 4 + quad) ^ x) * 8];
        qb2 = *(const half8*)&qh[16 + n][((2 * 4 + quad) ^ x) * 8];
        qb3 = *(const half8*)&qh[16 + n][((3 * 4 + quad) ^ x) * 8];
    }

    // ---- P3: pass A — 16 chunks x 64 keys; 8 MFMA + running max, no score store ----
    float m1a = -3.4e38f, m1b = -3.4e38f;
    int   i1a = 0, i1b = 0;
    for (int ch = 0; ch < 16; ++ch) {
        int kb = ch * 64 + wid * 16;
        const _Float16* kp = kh + (long)(kb + n) * CDIM + quad * 8;
        half8 a0 = *(const half8*)(kp + 0);
        half8 a1 = *(const half8*)(kp + 32);
        half8 a2 = *(const half8*)(kp + 64);
        half8 a3 = *(const half8*)(kp + 96);
        floatx4 accA = {0.f, 0.f, 0.f, 0.f};
        floatx4 accB = {0.f, 0.f, 0.f, 0.f};
        accA = MFMA16(a0, qa0, accA, 0, 0, 0);
        accA = MFMA16(a1, qa1, accA, 0, 0, 0);
        accA = MFMA16(a2, qa2, accA, 0, 0, 0);
        accA = MFMA16(a3, qa3, accA, 0, 0, 0);
        accB = MFMA16(a0, qb0, accB, 0, 0, 0);
        accB = MFMA16(a1, qb1, accB, 0, 0, 0);
        accB = MFMA16(a2, qb2, accB, 0, 0, 0);
        accB = MFMA16(a3, qb3, accB, 0, 0, 0);
        int keyb = kb + quad * 4;     // C layout: m = quad*4 + reg
        #pragma unroll
        for (int r = 0; r < 4; ++r) {
            float sA = accA[r], sB = accB[r];
            if (sA > m1a) { m1a = sA; i1a = keyb + r; }
            if (sB > m1b) { m1b = sB; i1b = keyb + r; }
        }
    }

    // ---- P4: merge running max across quads (same q-row, disjoint keys) ----
    {
        float om; int oi;
        om = __shfl_xor(m1a, 16); oi = __shfl_xor(i1a, 16);
        if (om > m1a || (om == m1a && oi < i1a)) { m1a = om; i1a = oi; }
        om = __shfl_xor(m1a, 32); oi = __shfl_xor(i1a, 32);
        if (om > m1a || (om == m1a && oi < i1a)) { m1a = om; i1a = oi; }
        om = __shfl_xor(m1b, 16); oi = __shfl_xor(i1b, 16);
        if (om > m1b || (om == m1b && oi < i1b)) { m1b = om; i1b = oi; }
        om = __shfl_xor(m1b, 32); oi = __shfl_xor(i1b, 32);
        if (om > m1b || (om == m1b && oi < i1b)) { m1b = om; i1b = oi; }
    }
    if (lane < 16) {
        wm1[wid][n]      = m1a; wi1[wid][n]      = i1a;
        wm1[wid][16 + n] = m1b; wi1[wid][16 + n] = i1b;
    }
    __syncthreads();

    // ---- P5: merge across waves; rigorous candidate threshold ----
    if (t < T_ROWS) {
        float M1 = wm1[0][t]; int I1 = wi1[0][t];
        for (int w = 1; w < 4; ++w) {
            float om = wm1[w][t]; int oi = wi1[w][t];
            if (om > M1 || (om == M1 && oi < I1)) { M1 = om; I1 = oi; }
        }
        float qn2 = 0.f;
        for (int j = 0; j < 16; ++j) qn2 += qss[t][j];
        float qn = sqrtf(qn2);
        // fp16 rounding: |s~ - s| <= 2^-10*1.01*||q||*||k||max(<=17) + fp32-acc slack
        float e1 = 0.0168f * qn + 0.002f;
        // pass B compares bit-identical s~ values, so 2*e1 (+ tiny slack) suffices
        rowT[t]   = M1 - 2.f * e1 - 0.02f;
        rowI1s[t] = I1;
    }
    __syncthreads();

    // ---- P6: pass B — identical MFMA chain; collect candidates >= threshold ----
    {
        float thrA = rowT[n], thrB = rowT[16 + n];
        for (int ch = 0; ch < 16; ++ch) {
            int kb = ch * 64 + wid * 16;
            const _Float16* kp = kh + (long)(kb + n) * CDIM + quad * 8;
            half8 a0 = *(const half8*)(kp + 0);
            half8 a1 = *(const half8*)(kp + 32);
            half8 a2 = *(const half8*)(kp + 64);
            half8 a3 = *(const half8*)(kp + 96);
            floatx4 accA = {0.f, 0.f, 0.f, 0.f};
            floatx4 accB = {0.f, 0.f, 0.f, 0.f};
            accA = MFMA16(a0, qa0, accA, 0, 0, 0);
            accA = MFMA16(a1, qa1, accA, 0, 0, 0);
            accA = MFMA16(a2, qa2, accA, 0, 0, 0);
            accA = MFMA16(a3, qa3, accA, 0, 0, 0);
            accB = MFMA16(a0, qb0, accB, 0, 0, 0);
            accB = MFMA16(a1, qb1, accB, 0, 0, 0);
            accB = MFMA16(a2, qb2, accB, 0, 0, 0);
            accB = MFMA16(a3, qb3, accB, 0, 0, 0);
            int keyb = kb + quad * 4;
            #pragma unroll
            for (int r = 0; r < 4; ++r) {
                if (accA[r] >= thrA) {
                    int pos = atomicAdd(&candCnt[n], 1);
                    if (pos < 8) candKey[n][pos] = keyb + r; else rowOvf[n] = 1;
                }
                if (accB[r] >= thrB) {
                    int pos = atomicAdd(&candCnt[16 + n], 1);
                    if (pos < 8) candKey[16 + n][pos] = keyb + r; else rowOvf[16 + n] = 1;
                }
            }
        }
    }
    __syncthreads();

    // ---- P7: exact fp32 rescoring of candidates; atomicMax packed (score,1023-key) ----
    {
        int row = t >> 3, slot = t & 7;    // 32 rows x 8 candidate slots
        int cnt = candCnt[row];
        if (!rowOvf[row] && slot < cnt) {
            int key = candKey[row][slot];
            const float* qp  = q + (g0 + row) * CDIM;
            const float* kp2 = keys + (long)key * CDIM;
            float acc0 = 0.f, acc1 = 0.f;
            for (int c = 0; c < CDIM; c += 8) {
                float4 qa = *(const float4*)(qp + c);
                float4 ka = *(const float4*)(kp2 + c);
                float4 qb = *(const float4*)(qp + c + 4);
                float4 kb4 = *(const float4*)(kp2 + c + 4);
                acc0 += qa.x*ka.x + qa.y*ka.y + qa.z*ka.z + qa.w*ka.w;
                acc1 += qb.x*kb4.x + qb.y*kb4.y + qb.z*kb4.z + qb.w*kb4.w;
            }
            FU su; su.f = acc0 + acc1;
            unsigned ord = (su.u & 0x80000000u) ? ~su.u : (su.u | 0x80000000u);
            unsigned long long enc = ((unsigned long long)ord << 32) | (unsigned)(1023 - key);
            atomicMax(&rowBest[row], enc);
        }
        // overflow fallback: exact rescan of all 1024 keys (rigor path, ~never taken)
        for (int rr = 0; rr < T_ROWS; ++rr) {
            if (rowOvf[rr]) {
                const float* qp = q + (g0 + rr) * CDIM;
                #pragma unroll
                for (int kkk = 0; kkk < 4; ++kkk) {
                    int key = t * 4 + kkk;
                    const float* kp2 = keys + (long)key * CDIM;
                    float acc0 = 0.f, acc1 = 0.f;
                    for (int c = 0; c < CDIM; c += 8) {
                        float4 qa = *(const float4*)(qp + c);
                        float4 ka = *(const float4*)(kp2 + c);
                        float4 qb = *(const float4*)(qp + c + 4);
                        float4 kb4 = *(const float4*)(kp2 + c + 4);
                        acc0 += qa.x*ka.x + qa.y*ka.y + qa.z*ka.z + qa.w*ka.w;
                        acc1 += qb.x*kb4.x + qb.y*kb4.y + qb.z*kb4.z + qb.w*kb4.w;
                    }
                    FU su; su.f = acc0 + acc1;
                    unsigned ord = (su.u & 0x80000000u) ? ~su.u : (su.u | 0x80000000u);
                    unsigned long long enc = ((unsigned long long)ord << 32) | (unsigned)(1023 - key);
                    atomicMax(&rowBest[rr], enc);
                }
            }
        }
    }
    __syncthreads();

    // ---- P8: decode winning index ----
    if (t < T_ROWS) {
        unsigned long long b = rowBest[t];
        rowIdx[t] = b ? (1023 - (int)(unsigned)(b & 0xffffffffull)) : rowI1s[t];
    }
    __syncthreads();

    // ---- P9: fused gather: sum (q-k)^2 and (r-v)^2 in fp32 ----
    {
        int row0 = t >> 4, c8 = t & 15;
        #pragma unroll
        for (int h = 0; h < 2; ++h) {
            int rr = row0 + h * 16;
            int idx = rowIdx[rr];
            long g = g0 + rr;
            const float4* qp  = (const float4*)(q    + g * CDIM + c8 * 8);
            const float4* kp2 = (const float4*)(keys + (long)idx * CDIM + c8 * 8);
            const float4* rp  = (const float4*)(rep  + g * CDIM + c8 * 8);
            const float4* vp  = (const float4*)(vals + (long)idx * CDIM + c8 * 8);
            float kg = 0.f, vg = 0.f;
            #pragma unroll
            for (int hh = 0; hh < 2; ++hh) {
                float4 qa = qp[hh], ka = kp2[hh], ra = rp[hh], va = vp[hh];
                float d0 = qa.x - ka.x, d1 = qa.y - ka.y, d2 = qa.z - ka.z, d3 = qa.w - ka.w;
                kg += d0*d0 + d1*d1 + d2*d2 + d3*d3;
                float e0 = ra.x - va.x, e1 = ra.y - va.y, e2 = ra.z - va.z, e3 = ra.w - va.w;
                vg += e0*e0 + e1*e1 + e2*e2 + e3*e3;
            }
            kgp[rr][c8] = kg; vgp[rr][c8] = vg;
        }
    }
    __syncthreads();
    if (t < T_ROWS) {
        float a = 0.f, b = 0.f;
        for (int j = 0; j < 16; ++j) { a += kgp[t][j]; b += vgp[t][j]; }
        long g = g0 + t;
        out[g] = a;
        out[NROWS + g] = b;
    }
}

extern "C" void kernel_launch(void* const* d_in, const int* in_sizes, int n_in,
                              void* d_out, int out_size, void* d_ws, size_t ws_size,
                              hipStream_t stream) {
    const float* q    = (const float*)d_in[0];  // trend_representation
    const float* rep  = (const float*)d_in[1];  // representation
    const float* keys = (const float*)d_in[2];
    const float* vals = (const float*)d_in[3];
    _Float16* kh = (_Float16*)d_ws;             // 256 KB fp16 key cache

    cvt_keys_kernel<<<128, 256, 0, stream>>>(keys, kh);
    gather_main<<<NROWS / T_ROWS, 256, 0, stream>>>(q, rep, keys, vals, kh,
                                                    (float*)d_out);
}